// Round 8
// baseline (1044.362 us; speedup 1.0000x reference)
//
#include <hip/hip_runtime.h>
#include <hip/hip_bf16.h>

// Sinkhorn object matching, scaling-vector formulation, fp8 iteration,
// PERSISTENT kernel v4 = R5's hot-line barrier + R7's write-once x ring.
//   S = Q R^T (4096x4096, D=256), K0 = exp(S_aug/0.1), dustbin row/col = z
//   100x: u = 1/(K0 v); v = 1/(K0^T u);  K = diag(u) K0 diag(v); P interior.
// Block b (256 blocks, 1024 thr) holds rows [16b,16b+16) of A8=fp8(K0) AND of
// T8=fp8(K0^T) in LDS. 1 block/CU -> 256 blocks co-resident.
// Gen g=1..200 writes x_g into ring slot g (write-once per dispatch, sc0sc1
// stores to LLC). Consumers read slots with sc0 (L2-cacheable: L2 is
// invalidated at kernel start and a slot is write-once-then-read within the
// dispatch, so no stale copy can exist).
// Arrival: monotonic atomics on HOT lines reused every gen (8 group counters
// 64B apart + master + gen flag) -> no cold-line misses, no resets, no races:
// group completer detects ret==32g-1, master completer ret==8g-1, then
// stores gen=g. Release: t0 of each block polls the single hot gen word.
// All sync objects zeroed by init_sync each call -> deterministic replays.

#define MROWS 4096
#define NCOLS 4096
#define DDIM 256
#define MP1 4097
#define INV_EPS 10.0f
#define NBLK 256
#define XSLOT 4160                 // floats per ring slot (16640 B, 64B mult)
#define BAR_DW 160                 // 8 group ctrs (16-dw apart) + master + gen

typedef __attribute__((ext_vector_type(8))) short bf16x8;
typedef __attribute__((ext_vector_type(4))) float f32x4;
typedef __attribute__((ext_vector_type(2))) float f32x2;
typedef __attribute__((ext_vector_type(4))) unsigned short u16x4;

static __device__ __forceinline__ unsigned short f2bf(float f) {
  __hip_bfloat16 h = __float2bfloat16(f);
  union { __hip_bfloat16 h; unsigned short s; } c;
  c.h = h;
  return c.s;
}

// strip load: L1-bypass, L2-cacheable (write-once slots -> no staleness).
// waitcnt inside the asm (rule #18).
static __device__ __forceinline__ void ld_strip(const float* ps, float4& xv) {
  asm volatile("global_load_dwordx4 %0, %1, off sc0\n\t"
               "s_waitcnt vmcnt(0)"
               : "=v"(xv) : "v"(ps) : "memory");
}
static __device__ __forceinline__ void ld_strip_dust(const float* ps, const float* pd,
                                                     float4& xv, float& xd) {
  asm volatile("global_load_dwordx4 %0, %2, off sc0\n\t"
               "global_load_dword %1, %3, off sc0\n\t"
               "s_waitcnt vmcnt(0)"
               : "=v"(xv), "=v"(xd)
               : "v"(ps), "v"(pd)
               : "memory");
}
// coherent store to the device coherence point (LLC)
static __device__ __forceinline__ void st_coherent(float* p, float x) {
  asm volatile("global_store_dword %0, %1, off sc0 sc1" :: "v"(p), "v"(x) : "memory");
}
// uncached flag load
static __device__ __forceinline__ unsigned ld_flagc(const unsigned* p) {
  unsigned r;
  asm volatile("global_load_dword %0, %1, off sc0 sc1\n\t"
               "s_waitcnt vmcnt(0)"
               : "=v"(r) : "v"(p) : "memory");
  return r;
}

// ---------------------------------------------------------------------------
// MFMA bf16 GEMM: 128x128 tile, 4 waves (2x2), wave = 64x64 via 4x4 frags of
// 16x16x32. MODE 0: kv=exp(10S) -> fp8 A8[row][col], fp8 T8[col][row].
// MODE 1: val = u[row]*exp(10S)*v[col] -> fp32 K (stride MP1) and P.
// ---------------------------------------------------------------------------
template <int MODE>
__global__ __launch_bounds__(256) void mfma_gemm_kernel(
    const float* __restrict__ Q, const float* __restrict__ R,
    unsigned char* __restrict__ A8, unsigned char* __restrict__ T8,
    float* __restrict__ Kf, float* __restrict__ P,
    const float* __restrict__ u, const float* __restrict__ v)
{
  __shared__ unsigned short Qs[128][40];
  __shared__ unsigned short Rs[128][40];

  const int tid = threadIdx.x;
  const int lane = tid & 63;
  const int wid = tid >> 6;
  const int wy = wid >> 1;
  const int wx = wid & 1;
  const int rb = blockIdx.y * 128;
  const int cb = blockIdx.x * 128;
  const int lr = tid >> 3;
  const int lf = (tid & 7) * 4;

  f32x4 acc[4][4];
#pragma unroll
  for (int m = 0; m < 4; ++m)
#pragma unroll
    for (int n = 0; n < 4; ++n)
      acc[m][n] = (f32x4){0.f, 0.f, 0.f, 0.f};

  for (int k0 = 0; k0 < DDIM; k0 += 32) {
    float4 qv[4], rv[4];
#pragma unroll
    for (int i = 0; i < 4; ++i) {
      qv[i] = *reinterpret_cast<const float4*>(&Q[(size_t)(rb + lr + 32 * i) * DDIM + k0 + lf]);
      rv[i] = *reinterpret_cast<const float4*>(&R[(size_t)(cb + lr + 32 * i) * DDIM + k0 + lf]);
    }
    __syncthreads();
#pragma unroll
    for (int i = 0; i < 4; ++i) {
      u16x4 qs = {f2bf(qv[i].x), f2bf(qv[i].y), f2bf(qv[i].z), f2bf(qv[i].w)};
      u16x4 rs = {f2bf(rv[i].x), f2bf(rv[i].y), f2bf(rv[i].z), f2bf(rv[i].w)};
      *reinterpret_cast<u16x4*>(&Qs[lr + 32 * i][lf]) = qs;
      *reinterpret_cast<u16x4*>(&Rs[lr + 32 * i][lf]) = rs;
    }
    __syncthreads();

    const int ko = (lane >> 4) * 8;
    const int fr = lane & 15;
    bf16x8 af[4], bg[4];
#pragma unroll
    for (int m = 0; m < 4; ++m)
      af[m] = *reinterpret_cast<const bf16x8*>(&Qs[wy * 64 + m * 16 + fr][ko]);
#pragma unroll
    for (int n = 0; n < 4; ++n)
      bg[n] = *reinterpret_cast<const bf16x8*>(&Rs[wx * 64 + n * 16 + fr][ko]);
#pragma unroll
    for (int m = 0; m < 4; ++m)
#pragma unroll
      for (int n = 0; n < 4; ++n)
        acc[m][n] = __builtin_amdgcn_mfma_f32_16x16x32_bf16(af[m], bg[n], acc[m][n], 0, 0, 0);
  }

  // C/D layout (16x16x32): col = lane&15, row = (lane>>4)*4 + reg.
  const int r0 = (lane >> 4) * 4;
  const int fc = lane & 15;
#pragma unroll
  for (int m = 0; m < 4; ++m) {
    const int row0 = rb + wy * 64 + m * 16 + r0;
    float uu[4];
    if (MODE == 1) {
#pragma unroll
      for (int r = 0; r < 4; ++r) uu[r] = u[row0 + r];
    }
#pragma unroll
    for (int n = 0; n < 4; ++n) {
      const int col = cb + wx * 64 + n * 16 + fc;
      if (MODE == 0) {
        float kv[4];
#pragma unroll
        for (int r = 0; r < 4; ++r) kv[r] = __expf(acc[m][n][r] * INV_EPS);
        int packed = __builtin_amdgcn_cvt_pk_fp8_f32(kv[0], kv[1], 0, false);
        packed = __builtin_amdgcn_cvt_pk_fp8_f32(kv[2], kv[3], packed, true);
        *reinterpret_cast<unsigned int*>(&T8[(size_t)col * NCOLS + row0]) = (unsigned int)packed;
#pragma unroll
        for (int r = 0; r < 4; ++r)
          A8[(size_t)(row0 + r) * NCOLS + col] = (unsigned char)(((unsigned int)packed >> (8 * r)) & 0xffu);
      } else {
        const float vc = v[col];
#pragma unroll
        for (int r = 0; r < 4; ++r) {
          const float kv = __expf(acc[m][n][r] * INV_EPS);
          const float val = uu[r] * kv * vc;
          Kf[(size_t)(row0 + r) * MP1 + col] = val;
          P[(size_t)(row0 + r) * NCOLS + col] = val;
        }
      }
    }
  }
}

// ---------------------------------------------------------------------------
// ring slot 0 = ones (gen 0 = initial v); zero the hot barrier words.
// ---------------------------------------------------------------------------
__global__ void init_sync_kernel(float* __restrict__ xbuf, unsigned* __restrict__ bar)
{
  const int i = blockIdx.x * 1024 + threadIdx.x;
  if (i < MP1) xbuf[i] = 1.0f;
  if (i < BAR_DW) bar[i] = 0u;
}

// ---------------------------------------------------------------------------
// Final K dustbin row/col.
// ---------------------------------------------------------------------------
__global__ void edgeK_kernel(const float* __restrict__ zp, float* __restrict__ Kf,
                             const float* __restrict__ u, const float* __restrict__ v)
{
  const int i = blockIdx.x * 256 + threadIdx.x;
  if (i >= MP1) return;
  const float E = __expf(zp[0] * INV_EPS);
  Kf[(size_t)i * MP1 + NCOLS] = u[i] * E * v[NCOLS];
  Kf[(size_t)MROWS * MP1 + i] = u[MROWS] * E * v[i];
}

// ---------------------------------------------------------------------------
// Persistent Sinkhorn iteration kernel. 256 blocks x 1024 threads.
// Per gen g: t0 polls the hot gen word (>= g-1), __syncthreads releases the
// block; waves load their x strip from slot g-1 (sc0, L2-cached), compute 16
// partials over their 256-col strip, fold-butterfly reduce, scratch; wave0
// finale computes the block's 16 outputs, stores them to slot g (sc0sc1),
// vmcnt(0), then monotonic-atomic arrival: fetch_add(cg[b&7]); the ret==32g-1
// completer fetch_adds master; the ret==8g-1 completer stores gen=g.
// ---------------------------------------------------------------------------
__global__ __launch_bounds__(1024) void sinkhorn_persist_kernel(
    const unsigned char* __restrict__ A8, const unsigned char* __restrict__ T8,
    float* __restrict__ xbuf, const float* __restrict__ zp,
    unsigned* __restrict__ bar)
{
  __shared__ unsigned char lA[16 * 4096];
  __shared__ unsigned char lT[16 * 4096];
  __shared__ float scratch[2][16][17];
  __shared__ float dscr[2][16];

  const int tid = threadIdx.x;
  const int b = blockIdx.x;
  const int lane = tid & 63;
  const int w = tid >> 6;
  const float E = __expf(zp[0] * INV_EPS);
  const int rev4 = ((lane & 1) << 3) | ((lane & 2) << 1) | ((lane & 4) >> 1) | ((lane & 8) >> 3);

  unsigned* cg  = bar + ((b & 7) << 4);   // hot group counter (64B apart)
  unsigned* cm  = bar + 128;              // hot master counter
  unsigned* gen = bar + 144;              // hot generation flag

  // one-time: stage this block's A and T row-slices into LDS (64KB each)
  {
    const uint4* gA = reinterpret_cast<const uint4*>(A8 + (size_t)b * 16 * 4096);
    const uint4* gT = reinterpret_cast<const uint4*>(T8 + (size_t)b * 16 * 4096);
    uint4* sA = reinterpret_cast<uint4*>(lA);
    uint4* sT = reinterpret_cast<uint4*>(lT);
#pragma unroll
    for (int i = 0; i < 4; ++i) {
      sA[tid + 1024 * i] = gA[tid + 1024 * i];
      sT[tid + 1024 * i] = gT[tid + 1024 * i];
    }
  }
  __syncthreads();

  const int c0 = (w << 8) + (lane << 2);   // lane's 4-col strip base

  for (int g = 1; g <= 200; ++g) {
    const unsigned char* Kl = (g & 1) ? lA : lT;      // odd g: u = f(v) uses A
    const float* xin = xbuf + (size_t)(g - 1) * XSLOT;
    float* xout = xbuf + (size_t)g * XSLOT;
    const unsigned need = (unsigned)(g - 1);
    const int sb = g & 1;

    // ---- wait for gen g-1 (t0 polls one hot word) ----
    if (tid == 0) {
      unsigned gv = ld_flagc(gen);
      while (gv < need) {
        __builtin_amdgcn_s_sleep(1);
        gv = ld_flagc(gen);
      }
    }
    __syncthreads();

    // ---- load x strip (sc0: local-L2 hit after first toucher per XCD) ----
    float4 xv; float xd = 0.f;
    if (w == 0) ld_strip_dust(xin + c0, xin + 4096, xv, xd);
    else        ld_strip(xin + c0, xv);

    // ---- 16 row-partials over this lane's 4 cols ----
    float acc[16];
#pragma unroll
    for (int r = 0; r < 16; ++r) {
      const unsigned int aw = *reinterpret_cast<const unsigned int*>(Kl + r * 4096 + c0);
      const f32x2 lo = __builtin_amdgcn_cvt_pk_f32_fp8((int)aw, false);
      const f32x2 hi = __builtin_amdgcn_cvt_pk_f32_fp8((int)aw, true);
      acc[r] = lo.x * xv.x + lo.y * xv.y + hi.x * xv.z + hi.y * xv.w;
    }

    // ---- fold-butterfly: 16 regs x 64 lanes -> lane rev4(lane&15) ----
    float r8[8], r4[4], r2[2], r1;
    {
      const bool f0 = (lane & 1) != 0;
#pragma unroll
      for (int k = 0; k < 8; ++k) {
        const float send = f0 ? acc[k] : acc[k + 8];
        const float keep = f0 ? acc[k + 8] : acc[k];
        r8[k] = keep + __shfl_xor(send, 1, 64);
      }
      const bool f1 = (lane & 2) != 0;
#pragma unroll
      for (int k = 0; k < 4; ++k) {
        const float send = f1 ? r8[k] : r8[k + 4];
        const float keep = f1 ? r8[k + 4] : r8[k];
        r4[k] = keep + __shfl_xor(send, 2, 64);
      }
      const bool f2 = (lane & 4) != 0;
#pragma unroll
      for (int k = 0; k < 2; ++k) {
        const float send = f2 ? r4[k] : r4[k + 2];
        const float keep = f2 ? r4[k + 2] : r4[k];
        r2[k] = keep + __shfl_xor(send, 4, 64);
      }
      const bool f3 = (lane & 8) != 0;
      {
        const float send = f3 ? r2[0] : r2[1];
        const float keep = f3 ? r2[1] : r2[0];
        r1 = keep + __shfl_xor(send, 8, 64);
      }
      r1 += __shfl_xor(r1, 16, 64);
      r1 += __shfl_xor(r1, 32, 64);
    }
    if (lane < 16) scratch[sb][rev4][w] = r1;

    if (b == 0) {   // dustbin row needs sum of all x
      float sv = xv.x + xv.y + xv.z + xv.w;
      sv += __shfl_xor(sv, 1, 64);  sv += __shfl_xor(sv, 2, 64);
      sv += __shfl_xor(sv, 4, 64);  sv += __shfl_xor(sv, 8, 64);
      sv += __shfl_xor(sv, 16, 64); sv += __shfl_xor(sv, 32, 64);
      if (lane == 0) dscr[sb][w] = sv;
    }
    __syncthreads();

    // ---- finale: cross-wave sum, store outputs, monotonic arrival ----
    if (w == 0) {
      const int rr = lane >> 2, wq = (lane & 3) * 4;
      float s = scratch[sb][rr][wq] + scratch[sb][rr][wq + 1]
              + scratch[sb][rr][wq + 2] + scratch[sb][rr][wq + 3];
      s += __shfl_xor(s, 1, 64);
      s += __shfl_xor(s, 2, 64);
      if ((lane & 3) == 0)
        st_coherent(xout + (b << 4) + rr, 1.0f / (s + E * xd));
      if (b == 0) {
        float t = (lane < 16) ? dscr[sb][lane] : 0.f;
        t += __shfl_xor(t, 1, 64);  t += __shfl_xor(t, 2, 64);
        t += __shfl_xor(t, 4, 64);  t += __shfl_xor(t, 8, 64);
        t += __shfl_xor(t, 16, 64); t += __shfl_xor(t, 32, 64);
        if (lane == 0) st_coherent(xout + 4096, 1.0f / (E * (t + xd)));
      }
      asm volatile("s_waitcnt vmcnt(0)" ::: "memory");   // outputs at LLC
      if (lane == 0) {
        const unsigned a = __hip_atomic_fetch_add(cg, 1u, __ATOMIC_RELAXED,
                                                  __HIP_MEMORY_SCOPE_AGENT);
        if (a == 32u * (unsigned)g - 1u) {               // group completer
          const unsigned m = __hip_atomic_fetch_add(cm, 1u, __ATOMIC_RELAXED,
                                                    __HIP_MEMORY_SCOPE_AGENT);
          if (m == 8u * (unsigned)g - 1u)                // master completer
            __hip_atomic_store(gen, (unsigned)g, __ATOMIC_RELAXED,
                               __HIP_MEMORY_SCOPE_AGENT);
        }
      }
    }
  }
}

extern "C" void kernel_launch(void* const* d_in, const int* in_sizes, int n_in,
                              void* d_out, int out_size, void* d_ws, size_t ws_size,
                              hipStream_t stream) {
  const float* Q = (const float*)d_in[0];
  const float* R = (const float*)d_in[1];
  const float* z = (const float*)d_in[2];

  float* P = (float*)d_out;
  float* Kf = P + (size_t)MROWS * NCOLS;   // K-region of d_out

  unsigned char* A8 = (unsigned char*)d_ws;                   // 16.8 MB
  unsigned char* T8 = A8 + (size_t)MROWS * NCOLS;             // 16.8 MB
  float* xbuf = (float*)(T8 + (size_t)MROWS * NCOLS);         // 201 slots
  unsigned* bar = (unsigned*)(xbuf + (size_t)201 * XSLOT);    // 160 u32, hot

  const float* u_final = xbuf + (size_t)199 * XSLOT;   // gen 199 = last u
  const float* v_final = xbuf + (size_t)200 * XSLOT;   // gen 200 = last v

  mfma_gemm_kernel<0><<<dim3(32, 32), 256, 0, stream>>>(Q, R, A8, T8, nullptr, nullptr, nullptr, nullptr);
  init_sync_kernel<<<5, 1024, 0, stream>>>(xbuf, bar);
  sinkhorn_persist_kernel<<<NBLK, 1024, 0, stream>>>(A8, T8, xbuf, z, bar);
  mfma_gemm_kernel<1><<<dim3(32, 32), 256, 0, stream>>>(Q, R, nullptr, nullptr, Kf, P, u_final, v_final);
  edgeK_kernel<<<(MP1 + 255) / 256, 256, 0, stream>>>(z, Kf, u_final, v_final);
}

// Round 9
// 924.251 us; speedup vs baseline: 1.1300x; 1.1300x over previous
//
#include <hip/hip_runtime.h>
#include <hip/hip_bf16.h>

// Sinkhorn object matching, scaling-vector formulation, fp8 iteration,
// PERSISTENT kernel v5 = R5 (proven 808us) + flattened hot-line barrier.
//   S = Q R^T (4096x4096, D=256), K0 = exp(S_aug/0.1), dustbin row/col = z
//   100x: u = 1/(K0 v); v = 1/(K0^T u);  K = diag(u) K0 diag(v); P interior.
// Block b (256 blocks, 1024 thr) holds rows [16b,16b+16) of A8=fp8(K0) AND of
// T8=fp8(K0^T) in LDS. 1 block/CU -> 256 blocks co-resident.
// CRITICAL-PATH RULE (R7/R8 lesson): every global line touched per gen must be
// LLC-HOT (reused each gen). x ring = 4 hot slots (sc0sc1 everywhere);
// barrier = 8 hot group counters + ONE hot 32B release line.
// Arrival: block's wave0 stores its 16 outputs (sc0sc1), vmcnt(0), then
// fetch_add(cg[b&7]); the ret==32g-1 completer stores g into release[b&7].
// Release: wave0's 64 lanes poll release[lane&7] (1 tx), __all(>= g-1),
// then __syncthreads wakes the block. Monotonic counters -> no resets/races.

#define MROWS 4096
#define NCOLS 4096
#define DDIM 256
#define MP1 4097
#define INV_EPS 10.0f
#define NBLK 256
#define XSLOT 4160                 // floats per ring slot (16640 B, 64B mult)
#define BAR_DW 160                 // 8 group ctrs (16-dw apart) + release line

typedef __attribute__((ext_vector_type(8))) short bf16x8;
typedef __attribute__((ext_vector_type(4))) float f32x4;
typedef __attribute__((ext_vector_type(2))) float f32x2;
typedef __attribute__((ext_vector_type(4))) unsigned short u16x4;

static __device__ __forceinline__ unsigned short f2bf(float f) {
  __hip_bfloat16 h = __float2bfloat16(f);
  union { __hip_bfloat16 h; unsigned short s; } c;
  c.h = h;
  return c.s;
}

// Coherent (L1/L2-bypassing) accessors; waitcnt inside the asm (rule #18).
static __device__ __forceinline__ void ld_strip(const float* ps, float4& xv) {
  asm volatile("global_load_dwordx4 %0, %1, off sc0 sc1\n\t"
               "s_waitcnt vmcnt(0)"
               : "=v"(xv) : "v"(ps) : "memory");
}
static __device__ __forceinline__ void ld_strip_dust(const float* ps, const float* pd,
                                                     float4& xv, float& xd) {
  asm volatile("global_load_dwordx4 %0, %2, off sc0 sc1\n\t"
               "global_load_dword %1, %3, off sc0 sc1\n\t"
               "s_waitcnt vmcnt(0)"
               : "=v"(xv), "=v"(xd)
               : "v"(ps), "v"(pd)
               : "memory");
}
static __device__ __forceinline__ void st_coherent(float* p, float x) {
  asm volatile("global_store_dword %0, %1, off sc0 sc1" :: "v"(p), "v"(x) : "memory");
}
static __device__ __forceinline__ unsigned ld_flagc(const unsigned* p) {
  unsigned r;
  asm volatile("global_load_dword %0, %1, off sc0 sc1\n\t"
               "s_waitcnt vmcnt(0)"
               : "=v"(r) : "v"(p) : "memory");
  return r;
}
static __device__ __forceinline__ void st_flag(unsigned* p, unsigned x) {
  asm volatile("global_store_dword %0, %1, off sc0 sc1" :: "v"(p), "v"(x) : "memory");
}

// ---------------------------------------------------------------------------
// MFMA bf16 GEMM: 128x128 tile, 4 waves (2x2), wave = 64x64 via 4x4 frags of
// 16x16x32. MODE 0: kv=exp(10S) -> fp8 A8[row][col], fp8 T8[col][row].
// MODE 1: val = u[row]*exp(10S)*v[col] -> fp32 K (stride MP1) and P.
// ---------------------------------------------------------------------------
template <int MODE>
__global__ __launch_bounds__(256) void mfma_gemm_kernel(
    const float* __restrict__ Q, const float* __restrict__ R,
    unsigned char* __restrict__ A8, unsigned char* __restrict__ T8,
    float* __restrict__ Kf, float* __restrict__ P,
    const float* __restrict__ u, const float* __restrict__ v)
{
  __shared__ unsigned short Qs[128][40];
  __shared__ unsigned short Rs[128][40];

  const int tid = threadIdx.x;
  const int lane = tid & 63;
  const int wid = tid >> 6;
  const int wy = wid >> 1;
  const int wx = wid & 1;
  const int rb = blockIdx.y * 128;
  const int cb = blockIdx.x * 128;
  const int lr = tid >> 3;
  const int lf = (tid & 7) * 4;

  f32x4 acc[4][4];
#pragma unroll
  for (int m = 0; m < 4; ++m)
#pragma unroll
    for (int n = 0; n < 4; ++n)
      acc[m][n] = (f32x4){0.f, 0.f, 0.f, 0.f};

  for (int k0 = 0; k0 < DDIM; k0 += 32) {
    float4 qv[4], rv[4];
#pragma unroll
    for (int i = 0; i < 4; ++i) {
      qv[i] = *reinterpret_cast<const float4*>(&Q[(size_t)(rb + lr + 32 * i) * DDIM + k0 + lf]);
      rv[i] = *reinterpret_cast<const float4*>(&R[(size_t)(cb + lr + 32 * i) * DDIM + k0 + lf]);
    }
    __syncthreads();
#pragma unroll
    for (int i = 0; i < 4; ++i) {
      u16x4 qs = {f2bf(qv[i].x), f2bf(qv[i].y), f2bf(qv[i].z), f2bf(qv[i].w)};
      u16x4 rs = {f2bf(rv[i].x), f2bf(rv[i].y), f2bf(rv[i].z), f2bf(rv[i].w)};
      *reinterpret_cast<u16x4*>(&Qs[lr + 32 * i][lf]) = qs;
      *reinterpret_cast<u16x4*>(&Rs[lr + 32 * i][lf]) = rs;
    }
    __syncthreads();

    const int ko = (lane >> 4) * 8;
    const int fr = lane & 15;
    bf16x8 af[4], bg[4];
#pragma unroll
    for (int m = 0; m < 4; ++m)
      af[m] = *reinterpret_cast<const bf16x8*>(&Qs[wy * 64 + m * 16 + fr][ko]);
#pragma unroll
    for (int n = 0; n < 4; ++n)
      bg[n] = *reinterpret_cast<const bf16x8*>(&Rs[wx * 64 + n * 16 + fr][ko]);
#pragma unroll
    for (int m = 0; m < 4; ++m)
#pragma unroll
      for (int n = 0; n < 4; ++n)
        acc[m][n] = __builtin_amdgcn_mfma_f32_16x16x32_bf16(af[m], bg[n], acc[m][n], 0, 0, 0);
  }

  // C/D layout (16x16x32): col = lane&15, row = (lane>>4)*4 + reg.
  const int r0 = (lane >> 4) * 4;
  const int fc = lane & 15;
#pragma unroll
  for (int m = 0; m < 4; ++m) {
    const int row0 = rb + wy * 64 + m * 16 + r0;
    float uu[4];
    if (MODE == 1) {
#pragma unroll
      for (int r = 0; r < 4; ++r) uu[r] = u[row0 + r];
    }
#pragma unroll
    for (int n = 0; n < 4; ++n) {
      const int col = cb + wx * 64 + n * 16 + fc;
      if (MODE == 0) {
        float kv[4];
#pragma unroll
        for (int r = 0; r < 4; ++r) kv[r] = __expf(acc[m][n][r] * INV_EPS);
        int packed = __builtin_amdgcn_cvt_pk_fp8_f32(kv[0], kv[1], 0, false);
        packed = __builtin_amdgcn_cvt_pk_fp8_f32(kv[2], kv[3], packed, true);
        *reinterpret_cast<unsigned int*>(&T8[(size_t)col * NCOLS + row0]) = (unsigned int)packed;
#pragma unroll
        for (int r = 0; r < 4; ++r)
          A8[(size_t)(row0 + r) * NCOLS + col] = (unsigned char)(((unsigned int)packed >> (8 * r)) & 0xffu);
      } else {
        const float vc = v[col];
#pragma unroll
        for (int r = 0; r < 4; ++r) {
          const float kv = __expf(acc[m][n][r] * INV_EPS);
          const float val = uu[r] * kv * vc;
          Kf[(size_t)(row0 + r) * MP1 + col] = val;
          P[(size_t)(row0 + r) * NCOLS + col] = val;
        }
      }
    }
  }
}

// ---------------------------------------------------------------------------
// ring slot 0 = ones (gen 0 = initial v); zero the hot barrier words.
// ---------------------------------------------------------------------------
__global__ void init_sync_kernel(float* __restrict__ xbuf, unsigned* __restrict__ bar)
{
  const int i = blockIdx.x * 1024 + threadIdx.x;
  if (i < MP1) xbuf[i] = 1.0f;
  if (i < BAR_DW) bar[i] = 0u;
}

// ---------------------------------------------------------------------------
// Final K dustbin row/col.
// ---------------------------------------------------------------------------
__global__ void edgeK_kernel(const float* __restrict__ zp, float* __restrict__ Kf,
                             const float* __restrict__ u, const float* __restrict__ v)
{
  const int i = blockIdx.x * 256 + threadIdx.x;
  if (i >= MP1) return;
  const float E = __expf(zp[0] * INV_EPS);
  Kf[(size_t)i * MP1 + NCOLS] = u[i] * E * v[NCOLS];
  Kf[(size_t)MROWS * MP1 + i] = u[MROWS] * E * v[i];
}

// ---------------------------------------------------------------------------
// Persistent Sinkhorn iteration kernel. 256 blocks x 1024 threads.
// bar layout: cg[grp] = bar + grp*16 (8 hot counter lines, 64B apart);
//             release[0..7] = bar + 128 (ONE hot 32B line).
// ---------------------------------------------------------------------------
__global__ __launch_bounds__(1024) void sinkhorn_persist_kernel(
    const unsigned char* __restrict__ A8, const unsigned char* __restrict__ T8,
    float* __restrict__ xbuf, const float* __restrict__ zp,
    unsigned* __restrict__ bar)
{
  __shared__ unsigned char lA[16 * 4096];
  __shared__ unsigned char lT[16 * 4096];
  __shared__ float scratch[2][16][17];
  __shared__ float dscr[2][16];

  const int tid = threadIdx.x;
  const int b = blockIdx.x;
  const int lane = tid & 63;
  const int w = tid >> 6;
  const float E = __expf(zp[0] * INV_EPS);
  const int rev4 = ((lane & 1) << 3) | ((lane & 2) << 1) | ((lane & 4) >> 1) | ((lane & 8) >> 3);

  unsigned* cg = bar + ((b & 7) << 4);      // hot group counter (64B apart)
  unsigned* release = bar + 128;            // hot 32B release line (8 dwords)

  // one-time: stage this block's A and T row-slices into LDS (64KB each)
  {
    const uint4* gA = reinterpret_cast<const uint4*>(A8 + (size_t)b * 16 * 4096);
    const uint4* gT = reinterpret_cast<const uint4*>(T8 + (size_t)b * 16 * 4096);
    uint4* sA = reinterpret_cast<uint4*>(lA);
    uint4* sT = reinterpret_cast<uint4*>(lT);
#pragma unroll
    for (int i = 0; i < 4; ++i) {
      sA[tid + 1024 * i] = gA[tid + 1024 * i];
      sT[tid + 1024 * i] = gT[tid + 1024 * i];
    }
  }
  __syncthreads();

  const int c0 = (w << 8) + (lane << 2);   // lane's 4-col strip base

  for (int g = 1; g <= 200; ++g) {
    const unsigned char* Kl = (g & 1) ? lA : lT;      // odd g: u = f(v) uses A
    const float* xin = xbuf + (size_t)((g - 1) & 3) * XSLOT;
    float* xout = xbuf + (size_t)(g & 3) * XSLOT;
    const unsigned need = (unsigned)(g - 1);
    const int sb = g & 1;

    // ---- wait for gen g-1: wave0 polls the single release line ----
    if (w == 0) {
      unsigned fv = ld_flagc(release + (lane & 7));   // 64 lanes, 1 tx
      while (!__all((int)(fv >= need))) {
        __builtin_amdgcn_s_sleep(1);
        fv = ld_flagc(release + (lane & 7));
      }
    }
    __syncthreads();

    // ---- load x strip (sc0sc1, hot LLC lines) ----
    float4 xv; float xd = 0.f;
    if (w == 0) ld_strip_dust(xin + c0, xin + 4096, xv, xd);
    else        ld_strip(xin + c0, xv);

    // ---- 16 row-partials over this lane's 4 cols ----
    float acc[16];
#pragma unroll
    for (int r = 0; r < 16; ++r) {
      const unsigned int aw = *reinterpret_cast<const unsigned int*>(Kl + r * 4096 + c0);
      const f32x2 lo = __builtin_amdgcn_cvt_pk_f32_fp8((int)aw, false);
      const f32x2 hi = __builtin_amdgcn_cvt_pk_f32_fp8((int)aw, true);
      acc[r] = lo.x * xv.x + lo.y * xv.y + hi.x * xv.z + hi.y * xv.w;
    }

    // ---- fold-butterfly: 16 regs x 64 lanes -> lane rev4(lane&15) ----
    float r8[8], r4[4], r2[2], r1;
    {
      const bool f0 = (lane & 1) != 0;
#pragma unroll
      for (int k = 0; k < 8; ++k) {
        const float send = f0 ? acc[k] : acc[k + 8];
        const float keep = f0 ? acc[k + 8] : acc[k];
        r8[k] = keep + __shfl_xor(send, 1, 64);
      }
      const bool f1 = (lane & 2) != 0;
#pragma unroll
      for (int k = 0; k < 4; ++k) {
        const float send = f1 ? r8[k] : r8[k + 4];
        const float keep = f1 ? r8[k + 4] : r8[k];
        r4[k] = keep + __shfl_xor(send, 2, 64);
      }
      const bool f2 = (lane & 4) != 0;
#pragma unroll
      for (int k = 0; k < 2; ++k) {
        const float send = f2 ? r4[k] : r4[k + 2];
        const float keep = f2 ? r4[k + 2] : r4[k];
        r2[k] = keep + __shfl_xor(send, 4, 64);
      }
      const bool f3 = (lane & 8) != 0;
      {
        const float send = f3 ? r2[0] : r2[1];
        const float keep = f3 ? r2[1] : r2[0];
        r1 = keep + __shfl_xor(send, 8, 64);
      }
      r1 += __shfl_xor(r1, 16, 64);
      r1 += __shfl_xor(r1, 32, 64);
    }
    if (lane < 16) scratch[sb][rev4][w] = r1;

    if (b == 0) {   // dustbin row needs sum of all x
      float sv = xv.x + xv.y + xv.z + xv.w;
      sv += __shfl_xor(sv, 1, 64);  sv += __shfl_xor(sv, 2, 64);
      sv += __shfl_xor(sv, 4, 64);  sv += __shfl_xor(sv, 8, 64);
      sv += __shfl_xor(sv, 16, 64); sv += __shfl_xor(sv, 32, 64);
      if (lane == 0) dscr[sb][w] = sv;
    }
    __syncthreads();

    // ---- finale: cross-wave sum, store outputs, monotonic arrival ----
    if (w == 0) {
      const int rr = lane >> 2, wq = (lane & 3) * 4;
      float s = scratch[sb][rr][wq] + scratch[sb][rr][wq + 1]
              + scratch[sb][rr][wq + 2] + scratch[sb][rr][wq + 3];
      s += __shfl_xor(s, 1, 64);
      s += __shfl_xor(s, 2, 64);
      if ((lane & 3) == 0)
        st_coherent(xout + (b << 4) + rr, 1.0f / (s + E * xd));
      if (b == 0) {
        float t = (lane < 16) ? dscr[sb][lane] : 0.f;
        t += __shfl_xor(t, 1, 64);  t += __shfl_xor(t, 2, 64);
        t += __shfl_xor(t, 4, 64);  t += __shfl_xor(t, 8, 64);
        t += __shfl_xor(t, 16, 64); t += __shfl_xor(t, 32, 64);
        if (lane == 0) st_coherent(xout + 4096, 1.0f / (E * (t + xd)));
      }
      asm volatile("s_waitcnt vmcnt(0)" ::: "memory");   // outputs at LLC
      if (lane == 0) {
        const unsigned a = __hip_atomic_fetch_add(cg, 1u, __ATOMIC_RELAXED,
                                                  __HIP_MEMORY_SCOPE_AGENT);
        if (a == 32u * (unsigned)g - 1u)                 // group completer
          st_flag(release + (b & 7), (unsigned)g);       // direct release
      }
    }
  }
}

extern "C" void kernel_launch(void* const* d_in, const int* in_sizes, int n_in,
                              void* d_out, int out_size, void* d_ws, size_t ws_size,
                              hipStream_t stream) {
  const float* Q = (const float*)d_in[0];
  const float* R = (const float*)d_in[1];
  const float* z = (const float*)d_in[2];

  float* P = (float*)d_out;
  float* Kf = P + (size_t)MROWS * NCOLS;   // K-region of d_out

  unsigned char* A8 = (unsigned char*)d_ws;                   // 16.8 MB
  unsigned char* T8 = A8 + (size_t)MROWS * NCOLS;             // 16.8 MB
  float* xbuf = (float*)(T8 + (size_t)MROWS * NCOLS);         // 4 hot slots
  unsigned* bar = (unsigned*)(xbuf + (size_t)4 * XSLOT);      // 160 u32, hot

  const float* u_final = xbuf + (size_t)3 * XSLOT;   // gen 199 -> slot 3
  const float* v_final = xbuf;                       // gen 200 -> slot 0

  mfma_gemm_kernel<0><<<dim3(32, 32), 256, 0, stream>>>(Q, R, A8, T8, nullptr, nullptr, nullptr, nullptr);
  init_sync_kernel<<<5, 1024, 0, stream>>>(xbuf, bar);
  sinkhorn_persist_kernel<<<NBLK, 1024, 0, stream>>>(A8, T8, xbuf, z, bar);
  mfma_gemm_kernel<1><<<dim3(32, 32), 256, 0, stream>>>(Q, R, nullptr, nullptr, Kf, P, u_final, v_final);
  edgeK_kernel<<<(MP1 + 255) / 256, 256, 0, stream>>>(z, Kf, u_final, v_final);
}